// Round 6
// baseline (91.401 us; speedup 1.0000x reference)
//
#include <hip/hip_runtime.h>
#include <hip/hip_bf16.h>
#include <stdint.h>

// ---------------------------------------------------------------------------
// MultiHeadedSelfAttention: x[2,2048,1024] -> out[2,2048,1024] (fp32)
// prep(bf16, W^T, rope table) -> fused QKV GEMM (swapped-operand C^T frags,
// bias+RoPE epilogue fused, writes qb/kb/cv directly) -> V transpose ->
// banded flash attention (swapped-operand MFMA, exp2 softmax, cvt_pk P-pack).
// ---------------------------------------------------------------------------

typedef __attribute__((ext_vector_type(8))) short bf16x8;
typedef __attribute__((ext_vector_type(4))) short bf16x4;
typedef __attribute__((ext_vector_type(4))) float f32x4;

#define DEV __device__ __forceinline__

DEV ushort f2b(float f) {               // fp32 -> bf16 bits, round-nearest-even
  union { float f; uint32_t u; } v; v.f = f;
  uint32_t r = v.u + 0x7FFFu + ((v.u >> 16) & 1u);
  return (ushort)(r >> 16);
}
DEV float b2f(ushort u) {
  union { uint32_t u; float f; } v; v.u = ((uint32_t)u) << 16;
  return v.f;
}
DEV uint cvt_pk_bf16(float lo, float hi) {   // [bf16(lo) | bf16(hi)<<16], RNE
  uint r;
  asm("v_cvt_pk_bf16_f32 %0, %1, %2" : "=v"(r) : "v"(lo), "v"(hi));
  return r;
}
DEV float fast_exp2(float x) {
#if __has_builtin(__builtin_amdgcn_exp2f)
  return __builtin_amdgcn_exp2f(x);
#else
  return exp2f(x);
#endif
}

DEV void gload_lds16(const void* g, void* l) {
  __builtin_amdgcn_global_load_lds((const __attribute__((address_space(1))) void*)g,
                                   (__attribute__((address_space(3))) void*)l,
                                   16, 0, 0);
}

// ---------------------------------------------------------------------------
__global__ __launch_bounds__(256) void prep_x_kernel(const float* __restrict__ x,
                                                     ushort* __restrict__ xb) {
  int t = blockIdx.x * 256 + threadIdx.x;
  float4 v = ((const float4*)x)[t];
  bf16x4 o;
  o[0] = (short)f2b(v.x); o[1] = (short)f2b(v.y);
  o[2] = (short)f2b(v.z); o[3] = (short)f2b(v.w);
  *(bf16x4*)&xb[(size_t)t * 4] = o;
}

__global__ void prep_w_kernel(const float* __restrict__ wq, const float* __restrict__ wk,
                              const float* __restrict__ wv, ushort* __restrict__ wt) {
  __shared__ float tile[32][33];
  int which = blockIdx.z;
  const float* w = which == 0 ? wq : (which == 1 ? wk : wv);
  int n0 = blockIdx.x * 32, k0 = blockIdx.y * 32;
  tile[threadIdx.y][threadIdx.x] = w[(size_t)(k0 + threadIdx.y) * 1024 + n0 + threadIdx.x];
  __syncthreads();
  wt[((size_t)which * 1024 + n0 + threadIdx.y) * 1024 + k0 + threadIdx.x] =
      f2b(tile[threadIdx.x][threadIdx.y]);
}

__global__ __launch_bounds__(256) void rope_tab_kernel(float2* __restrict__ tab) {
  int t = blockIdx.x * 256 + threadIdx.x;          // 65536
  int i = t & 31, s = t >> 5;
  float theta = powf(10000.0f, -(float)i / 32.0f);
  float ang = (float)s * theta;
  tab[t] = make_float2(cosf(ang), sinf(ang));
}

// ---------------------------------------------------------------------------
// QKV GEMM: A = xb [4096][1024], Bt = wt [3072][1024].
// Swapped-operand MFMA -> C^T frags (m = llo, n = lhi*4+j): RoPE pairs are
// lane-local. Epilogue fuses bias + RoPE (+ q scale 0.125*log2e) and writes
// qb/kb [bh][s][hd] and cv [m][hd] (V region) directly. No C buffer.
__global__ __launch_bounds__(512, 2) void qkv_gemm_kernel(
    const ushort* __restrict__ A, const ushort* __restrict__ Bt,
    const float* __restrict__ bq, const float* __restrict__ bk,
    const float* __restrict__ bv, const float2* __restrict__ tab,
    ushort* __restrict__ qb, ushort* __restrict__ kb, ushort* __restrict__ cv) {
  const int K = 1024;
  __shared__ alignas(16) ushort sS[4][2][256 * 32];   // [buf][A/B][256 rows][32 k]

  int tid = threadIdx.x;
  int lane = tid & 63;
  int lhi = lane >> 4, llo = lane & 15;
  int wid = tid >> 6;
  int wr = wid >> 2, wc = wid & 3;                    // 2M x 4N waves

  int id = blockIdx.x;
  int wg = (id & 7) * 32 + (id >> 3);                 // XCD-grouped (256 = 8 x 32)
  int bm = wg >> 4, bn = wg & 15;                     // 16 x 16 tiles

  const ushort* Abase = A + (size_t)bm * 256 * K;
  const ushort* Bbase = Bt + (size_t)bn * 192 * K;

  f32x4 acc[8][3];
#pragma unroll
  for (int i = 0; i < 8; ++i)
#pragma unroll
    for (int j = 0; j < 3; ++j) acc[i][j] = (f32x4){0.f, 0.f, 0.f, 0.f};

  auto stage = [&](int kt, int bb) {                  // 4 gload_lds per thread
    int k0 = kt * 32;
#pragma unroll
    for (int c = 0; c < 2; ++c) {
      int idx = c * 512 + tid;                        // [0,1024): A rows 0..255
      int rowA = idx >> 2, col = (idx & 3) * 8;
      gload_lds16(Abase + (size_t)rowA * K + k0 + col, &sS[bb][0][idx * 8]);
      int rowB = rowA < 192 ? rowA : 191;             // clamp (rows 192..255 unused)
      gload_lds16(Bbase + (size_t)rowB * K + k0 + col, &sS[bb][1][idx * 8]);
    }
  };

  stage(0, 0); stage(1, 1); stage(2, 2);              // 12 loads in flight

  for (int kt = 0; kt < 32; ++kt) {
    // wait for tile kt (own oldest 4 loads); tiles kt+1, kt+2 stay in flight
    if (kt <= 29)      asm volatile("s_waitcnt vmcnt(8)" ::: "memory");
    else if (kt == 30) asm volatile("s_waitcnt vmcnt(4)" ::: "memory");
    else               asm volatile("s_waitcnt vmcnt(0)" ::: "memory");
    __builtin_amdgcn_sched_barrier(0);
    __builtin_amdgcn_s_barrier();   // tile kt resident everywhere; buf (kt-1)%4 free
    __builtin_amdgcn_sched_barrier(0);

    if (kt + 3 < 32) stage(kt + 3, (kt + 3) & 3);     // refill freed buffer early
    __builtin_amdgcn_sched_barrier(0);

    int bb = kt & 3;
    const ushort* pA = sS[bb][0];
    const ushort* pB = sS[bb][1];
    bf16x8 af[8], bfr[3];
#pragma unroll
    for (int mf = 0; mf < 8; ++mf)
      af[mf] = *(const bf16x8*)&pA[(wr * 128 + mf * 16 + llo) * 32 + lhi * 8];
#pragma unroll
    for (int nf = 0; nf < 3; ++nf)
      bfr[nf] = *(const bf16x8*)&pB[(wc * 48 + nf * 16 + llo) * 32 + lhi * 8];
    __builtin_amdgcn_s_setprio(1);
#pragma unroll
    for (int mf = 0; mf < 8; ++mf)
#pragma unroll
      for (int nf = 0; nf < 3; ++nf)   // swapped: C^T, n along regs
        acc[mf][nf] = __builtin_amdgcn_mfma_f32_16x16x32_bf16(bfr[nf], af[mf], acc[mf][nf], 0, 0, 0);
    __builtin_amdgcn_s_setprio(0);
  }

  // fused epilogue: bias + RoPE (+ scale) -> qb/kb; bias -> cv
  const float SCL = 0.18033688011112042f;             // 0.125 * log2(e)
#pragma unroll
  for (int mf = 0; mf < 8; ++mf) {
    int m = bm * 256 + wr * 128 + mf * 16 + llo;
    int s = m & 2047, bidx = m >> 11;
#pragma unroll
    for (int nf = 0; nf < 3; ++nf) {
      int nbase = bn * 192 + wc * 48 + nf * 16;       // wave-uniform region
      int n0 = nbase + lhi * 4;
      f32x4 a = acc[mf][nf];
      if (nbase < 1024) {                             // ---- q: bias+RoPE+scale
        float4 cs = *(const float4*)&tab[s * 32 + ((n0 & 63) >> 1)];
        float4 bb = *(const float4*)&bq[n0];
        float t0 = a[0] + bb.x, t1 = a[1] + bb.y;
        float t2 = a[2] + bb.z, t3 = a[3] + bb.w;
        uint2 ov;
        ov.x = cvt_pk_bf16((t0 * cs.x - t1 * cs.y) * SCL, (t1 * cs.x + t0 * cs.y) * SCL);
        ov.y = cvt_pk_bf16((t2 * cs.z - t3 * cs.w) * SCL, (t3 * cs.z + t2 * cs.w) * SCL);
        int h = n0 >> 6;
        *(uint2*)&qb[((size_t)(bidx * 16 + h) * 2048 + s) * 64 + (n0 & 63)] = ov;
      } else if (nbase < 2048) {                      // ---- k: bias+RoPE
        float4 cs = *(const float4*)&tab[s * 32 + ((n0 & 63) >> 1)];
        float4 bb = *(const float4*)&bk[n0 - 1024];
        float t0 = a[0] + bb.x, t1 = a[1] + bb.y;
        float t2 = a[2] + bb.z, t3 = a[3] + bb.w;
        uint2 ov;
        ov.x = cvt_pk_bf16(t0 * cs.x - t1 * cs.y, t1 * cs.x + t0 * cs.y);
        ov.y = cvt_pk_bf16(t2 * cs.z - t3 * cs.w, t3 * cs.z + t2 * cs.w);
        int h = (n0 >> 6) & 15;
        *(uint2*)&kb[((size_t)(bidx * 16 + h) * 2048 + s) * 64 + (n0 & 63)] = ov;
      } else {                                        // ---- v: bias only
        float4 bb = *(const float4*)&bv[n0 - 2048];
        uint2 ov;
        ov.x = cvt_pk_bf16(a[0] + bb.x, a[1] + bb.y);
        ov.y = cvt_pk_bf16(a[2] + bb.z, a[3] + bb.w);
        *(uint2*)&cv[(size_t)m * 1024 + (n0 - 2048)] = ov;
      }
    }
  }
}

// ---------------------------------------------------------------------------
// V transpose: cv [4096][1024] -> vt [32][64][2048] (bit-exact, bias already in)
__global__ __launch_bounds__(256) void epi_v_kernel(const ushort* __restrict__ cv,
                                                    ushort* __restrict__ vt) {
  __shared__ float lv[64][65];
  int bh = blockIdx.y; int h = bh & 15;
  int s0 = blockIdx.x * 64;
  int tid = threadIdx.x;
  size_t mbase = (size_t)(bh >> 4) * 2048 + s0;
#pragma unroll
  for (int ph = 0; ph < 2; ++ph) {
    int idx = ph * 256 + tid;
    int row = idx >> 3, col = (idx & 7) * 8;
    bf16x8 v = *(const bf16x8*)&cv[(mbase + row) * 1024 + h * 64 + col];
#pragma unroll
    for (int e = 0; e < 8; ++e) lv[row][col + e] = b2f((ushort)v[e]);
  }
  __syncthreads();
#pragma unroll
  for (int ph = 0; ph < 2; ++ph) {
    int idx = ph * 256 + tid;
    int hd = idx >> 3, s8 = (idx & 7) * 8;
    bf16x8 o;
#pragma unroll
    for (int e = 0; e < 8; ++e) o[e] = (short)f2b(lv[s8 + e][hd]);
    *(bf16x8*)&vt[((size_t)bh * 64 + hd) * 2048 + s0 + s8] = o;
  }
}

// ---------------------------------------------------------------------------
// banded flash attention, swapped-operand form. QBLK=128 (8 waves x 16 rows),
// KVBLK=64, reg-staged dbuf, exp2-domain softmax (scale baked into q),
// cvt_pk P packing, per-wave active-window guard, XCD-grouped bh.
__global__ __launch_bounds__(512) void attn_kernel(
    const ushort* __restrict__ qb, const ushort* __restrict__ kb,
    const ushort* __restrict__ vt, const int* __restrict__ kmask,
    const int* __restrict__ whist, float* __restrict__ out) {
  __shared__ alignas(16) ushort sK[64 * 64];       // [64 keys][64 hd], XOR-swizzled
  __shared__ alignas(16) ushort sV[64 * 72];       // [64 d][64 keys], pitch 72
  __shared__ alignas(16) uint   sPd[8][16 * 36];   // per-wave P [16 q][64 k] bf16, pitch 36 dw

  int tid = threadIdx.x;
  int lane = tid & 63, wid = tid >> 6;             // 8 waves
  int lhi = lane >> 4, llo = lane & 15;

  int id = blockIdx.x;                             // 512 blocks
  int xcd = id & 7, sub = id >> 3;                 // T1: same-bh blocks per XCD
  int bh = xcd * 4 + (sub >> 4);
  int qtile = sub & 15;
  int b = bh >> 4;
  int q0 = qtile * 128;
  int qw0 = q0 + wid * 16;
  int W = *whist;

  const ushort* qptr = qb + (size_t)bh * 2048 * 64;
  const ushort* kptr = kb + (size_t)bh * 2048 * 64;
  const ushort* vptr = vt + (size_t)bh * 64 * 2048;
  const int* mrow = kmask + b * 2048;

  bf16x8 qf0, qf1;                                 // Q frag, q = llo, hd halves
  {
    size_t base = (size_t)(qw0 + llo) * 64 + lhi * 8;
    qf0 = *(const bf16x8*)&qptr[base];
    qf1 = *(const bf16x8*)&qptr[base + 32];
  }

  float m_ = -1e30f, l_ = 0.f;                     // lane-local: q = qw0 + llo
  f32x4 o[4];                                      // O^T: d = nf*16 + lhi*4 + j, q = llo
#pragma unroll
  for (int nf = 0; nf < 4; ++nf) o[nf] = (f32x4){0.f, 0.f, 0.f, 0.f};

  int lo = q0 - (W - 1); if (lo < 0) lo = 0;
  int jt0 = lo & ~63;
  int nt = ((q0 + 128) - jt0) >> 6;                // tiles covering all 128 q rows

  bf16x8 kreg, vreg;
  int mreg;
  int srow = tid >> 3, sslot = tid & 7;            // 64 rows x 8 slots

  auto load_tile = [&](int jt) {                   // global -> regs (prefetch)
    kreg = *(const bf16x8*)&kptr[(size_t)(jt + srow) * 64 + sslot * 8];
    vreg = *(const bf16x8*)&vptr[(size_t)srow * 2048 + jt + sslot * 8];
    mreg = mrow[jt + lane];
  };

  load_tile(jt0);
  for (int it = 0; it < nt; ++it) {
    int jt = jt0 + it * 64;
    __syncthreads();                               // prev tile's LDS reads done
    *(bf16x8*)&sK[srow * 64 + ((sslot ^ (srow & 7)) * 8)] = kreg;
    *(bf16x8*)&sV[srow * 72 + sslot * 8] = vreg;
    unsigned long long pm = __ballot(mreg != 0);   // padded-key bitmask (wave-uniform)
    if (it + 1 < nt) load_tile(jt + 64);           // prefetch hides under compute
    __syncthreads();                               // LDS tile visible

    // per-wave window guard (wave-uniform; barriers stay outside)
    bool active = (jt <= qw0 + 15) && (jt + 63 >= qw0 - W + 1);
    if (active) {
      // S^T = K Q^T : sc[kb4] row = key offset (lhi*4+j), col = q (llo)
      f32x4 sc[4];
#pragma unroll
      for (int kb4 = 0; kb4 < 4; ++kb4) sc[kb4] = (f32x4){0.f, 0.f, 0.f, 0.f};
      __builtin_amdgcn_s_setprio(1);
#pragma unroll
      for (int ks = 0; ks < 2; ++ks) {
        bf16x8 qq = ks ? qf1 : qf0;
#pragma unroll
        for (int kb4 = 0; kb4 < 4; ++kb4) {
          int r = kb4 * 16 + llo;
          bf16x8 kf = *(const bf16x8*)&sK[r * 64 + (((ks * 4 + lhi) ^ (r & 7)) * 8)];
          sc[kb4] = __builtin_amdgcn_mfma_f32_16x16x32_bf16(kf, qq, sc[kb4], 0, 0, 0);
        }
      }
      __builtin_amdgcn_s_setprio(0);

      bool fast = (jt + 63 <= qw0) && (jt >= qw0 + 16 - W) && (pm == 0ull);
      float s[16];
      bool ok[16];
      if (fast) {
#pragma unroll
        for (int kb4 = 0; kb4 < 4; ++kb4)
#pragma unroll
          for (int j = 0; j < 4; ++j) s[kb4 * 4 + j] = sc[kb4][j];
      } else {
        int qi = qw0 + llo;
#pragma unroll
        for (int kb4 = 0; kb4 < 4; ++kb4) {
          uint nib = (uint)(pm >> (kb4 * 16 + lhi * 4)) & 0xFu;
#pragma unroll
          for (int j = 0; j < 4; ++j) {
            int key = jt + kb4 * 16 + lhi * 4 + j;
            bool k_ok = (key <= qi) && (qi - key < W) && !((nib >> j) & 1u);
            ok[kb4 * 4 + j] = k_ok;
            s[kb4 * 4 + j] = k_ok ? sc[kb4][j] : -1e30f;
          }
        }
      }

      // lane-local max over 16 + 2 shuffles across lhi groups
      float t01 = fmaxf(s[0], s[1]),  t23 = fmaxf(s[2], s[3]);
      float t45 = fmaxf(s[4], s[5]),  t67 = fmaxf(s[6], s[7]);
      float t89 = fmaxf(s[8], s[9]),  tab_ = fmaxf(s[10], s[11]);
      float tcd = fmaxf(s[12], s[13]), tef = fmaxf(s[14], s[15]);
      float t = fmaxf(fmaxf(fmaxf(t01, t23), fmaxf(t45, t67)),
                      fmaxf(fmaxf(t89, tab_), fmaxf(tcd, tef)));
      t = fmaxf(t, __shfl_xor(t, 16));
      t = fmaxf(t, __shfl_xor(t, 32));

      if (t > m_ + 8.f) {                          // defer-max (T13), log2 domain
        float fac = fast_exp2(m_ - t);
        l_ *= fac;
#pragma unroll
        for (int nf = 0; nf < 4; ++nf) o[nf] *= fac;
        m_ = t;
      }

      float p[16];
      if (fast) {
#pragma unroll
        for (int i = 0; i < 16; ++i) p[i] = fast_exp2(s[i] - m_);
      } else {                                     // masked p exactly 0
#pragma unroll
        for (int i = 0; i < 16; ++i) p[i] = ok[i] ? fast_exp2(s[i] - m_) : 0.f;
      }
      float ps = ((p[0] + p[1]) + (p[2] + p[3])) + ((p[4] + p[5]) + (p[6] + p[7]))
               + ((p[8] + p[9]) + (p[10] + p[11])) + ((p[12] + p[13]) + (p[14] + p[15]));
      ps += __shfl_xor(ps, 16);
      ps += __shfl_xor(ps, 32);
      l_ += ps;

      // P (fp32, lane q=llo, keys kb4*16+lhi*4+j) -> wave-private LDS as bf16
#pragma unroll
      for (int kb4 = 0; kb4 < 4; ++kb4) {
        uint d0 = cvt_pk_bf16(p[kb4 * 4 + 0], p[kb4 * 4 + 1]);
        uint d1 = cvt_pk_bf16(p[kb4 * 4 + 2], p[kb4 * 4 + 3]);
        sPd[wid][llo * 36 + kb4 * 8 + lhi * 2]     = d0;
        sPd[wid][llo * 36 + kb4 * 8 + lhi * 2 + 1] = d1;
      }
      bf16x8 pf0 = *(const bf16x8*)&sPd[wid][llo * 36 + lhi * 4];        // keys 0..31
      bf16x8 pf1 = *(const bf16x8*)&sPd[wid][llo * 36 + 16 + lhi * 4];   // keys 32..63

      // O^T += V^T P^T : o row = d offset, col = q
      __builtin_amdgcn_s_setprio(1);
#pragma unroll
      for (int nf = 0; nf < 4; ++nf) {
        bf16x8 vf0 = *(const bf16x8*)&sV[(nf * 16 + llo) * 72 + lhi * 8];
        bf16x8 vf1 = *(const bf16x8*)&sV[(nf * 16 + llo) * 72 + 32 + lhi * 8];
        o[nf] = __builtin_amdgcn_mfma_f32_16x16x32_bf16(vf0, pf0, o[nf], 0, 0, 0);
        o[nf] = __builtin_amdgcn_mfma_f32_16x16x32_bf16(vf1, pf1, o[nf], 0, 0, 0);
      }
      __builtin_amdgcn_s_setprio(0);
    }
  }

  float inv = 1.f / l_;
  int qi = qw0 + llo;
  size_t obase = ((size_t)b * 2048 + qi) * 1024 + (bh & 15) * 64 + lhi * 4;
#pragma unroll
  for (int nf = 0; nf < 4; ++nf) {
    float4 st = make_float4(o[nf][0] * inv, o[nf][1] * inv, o[nf][2] * inv, o[nf][3] * inv);
    *(float4*)&out[obase + nf * 16] = st;
  }
}

// ---------------------------------------------------------------------------
extern "C" void kernel_launch(void* const* d_in, const int* in_sizes, int n_in,
                              void* d_out, int out_size, void* d_ws, size_t ws_size,
                              hipStream_t stream) {
  const float* x  = (const float*)d_in[0];
  const float* wq = (const float*)d_in[1];
  const float* bq = (const float*)d_in[2];
  const float* wk = (const float*)d_in[3];
  const float* bk = (const float*)d_in[4];
  const float* wv = (const float*)d_in[5];
  const float* bv = (const float*)d_in[6];
  const int* kmask = (const int*)d_in[7];
  const int* whist = (const int*)d_in[8];
  float* out = (float*)d_out;

  char* ws = (char*)d_ws;
  ushort* xb  = (ushort*)(ws);                       // [4096][1024] bf16   8 MB
  ushort* wt  = (ushort*)(ws + (8ull  << 20));       // [3072][1024] bf16   6 MB
  ushort* cv  = (ushort*)(ws + (14ull << 20));       // [4096][1024] bf16   8 MB
  ushort* qb  = (ushort*)(ws + (22ull << 20));       // [32][2048][64]      8 MB
  ushort* kb  = (ushort*)(ws + (30ull << 20));       // [32][2048][64]      8 MB
  ushort* vt  = (ushort*)(ws + (38ull << 20));       // [32][64][2048]      8 MB
  float2* tab = (float2*)(ws + (46ull << 20));       // [2048][32] float2  .5 MB

  prep_x_kernel<<<4096, 256, 0, stream>>>(x, xb);
  prep_w_kernel<<<dim3(32, 32, 3), dim3(32, 32, 1), 0, stream>>>(wq, wk, wv, wt);
  rope_tab_kernel<<<256, 256, 0, stream>>>(tab);
  qkv_gemm_kernel<<<256, 512, 0, stream>>>(xb, wt, bq, bk, bv, tab, qb, kb, cv);
  epi_v_kernel<<<dim3(32, 32), 256, 0, stream>>>(cv, vt);
  attn_kernel<<<512, 512, 0, stream>>>(qb, kb, vt, kmask, whist, out);
}